// Round 10
// baseline (475.081 us; speedup 1.0000x reference)
//
#include <hip/hip_runtime.h>
#include <hip/hip_bf16.h>

#define SEQ   20
#define PRED  30
#define TSTEPS (SEQ + PRED)
#define PEDS  16384
#define EMB   64
#define RNN   128
#define KTOT  192
#define PB    32
#define NT    512

typedef _Float16 half8 __attribute__((ext_vector_type(8)));
typedef _Float16 half4 __attribute__((ext_vector_type(4)));
typedef __attribute__((ext_vector_type(4))) float f32x4;

__device__ __forceinline__ float sigm(float x) {
    return 1.f / (1.f + __expf(-x));
}
__device__ __forceinline__ float tanhfast(float x) {
    x = fmaxf(x, -15.f);
    float e = __expf(-2.f * x);
    return (1.f - e) / (1.f + e);
}

// B fragments (f16) pre-permuted: idx = ((kt*32 + nt)*64 + l)*8 + i ; nt = g*8 + jt
// row n = g*128 + jt*16 + (l&15) ; k = kt*32 + (l>>4)*8 + i
// W_cat[n][k]: k<64 -> W_ih[n][k], else W_hh[n][k-64].
// ewp[ke][4] = {Wemb[ke][0], Wemb[ke][1], bemb[ke], 0}
__global__ void prep_kernel(const float* __restrict__ Wih, const float* __restrict__ Whh,
                            const float* __restrict__ Wemb, const float* __restrict__ bemb,
                            _Float16* __restrict__ Bp, float* __restrict__ ewp) {
    int t = blockIdx.x * blockDim.x + threadIdx.x;
    if (t < 64) {
        ewp[t * 4 + 0] = Wemb[t * 2 + 0];
        ewp[t * 4 + 1] = Wemb[t * 2 + 1];
        ewp[t * 4 + 2] = bemb[t];
        ewp[t * 4 + 3] = 0.f;
    }
    if (t >= 6 * 32 * 64 * 8) return;
    int i  = t & 7;
    int l  = (t >> 3) & 63;
    int nt = (t >> 9) & 31;
    int kt = t >> 14;
    int n = (nt >> 3) * RNN + (nt & 7) * 16 + (l & 15);
    int k = kt * 32 + ((l >> 4) << 3) + i;
    float val = (k < EMB) ? Wih[n * EMB + k] : Whh[n * RNN + (k - EMB)];
    Bp[t] = (_Float16)val;
}

// PB=32 -> 512 blocks -> 2 blocks/CU (LDS 77.3 KB each, 155 KB total).
// Two blocks = independent barrier domains -> phases overlap across blocks.
// launch_bounds(512,2): empirically 2 blocks/CU promise -> 128 VGPR cap.
__global__ __launch_bounds__(NT, 2) void lstm_kernel(
    const float* __restrict__ obs,
    const float* __restrict__ ewp,
    const float* __restrict__ bih,  const float* __restrict__ bhh,
    const _Float16* __restrict__ Bp,
    const float* __restrict__ Wout, const float* __restrict__ bout,
    float* __restrict__ out)
{
    // A = [e(64) ; h(128)] single-plane f16, row-major [32 ped][192 k] (384 B rows),
    // XOR-swizzled. B staged per-kt (32 KB slices) double-buffered, per-wave-private.
    __shared__ __align__(16) char smA[PB * 384];    // 12 KB
    __shared__ __align__(16) char smB[2 * 32768];   // 64 KB B dbuf
    __shared__ float part[PB * 2 * 4];
    __shared__ float outs[PB * 2];

    const int tid = threadIdx.x;
    const int l   = tid & 63;
    const int w   = __builtin_amdgcn_readfirstlane(tid >> 6);  // wave 0..7

    // zero A (h region must be 0 at step 0)
    for (int r = tid; r < (PB * 384) / 4; r += NT) ((int*)smA)[r] = 0;

    const int jlane = w * 16 + (l & 15);  // this lane's j column
    const int lrow  = (l >> 4) << 2;      // C/D row base
    const int kgrp  = (l >> 4) << 3;      // A/B k-group base

    float bias[4];
#pragma unroll
    for (int g = 0; g < 4; ++g) {
        int n = g * RNN + jlane;
        bias[g] = bih[n] + bhh[n];
    }

    // E-phase mapping: thread = (ped = tid&31, kq = tid>>5); 4 k's per thread.
    const int eped = tid & 31;
    const int ekq  = tid >> 5;  // 0..15
    const int epg  = blockIdx.x * PB + eped;
    f32x4 ew[4];
#pragma unroll
    for (int q = 0; q < 4; ++q)
        ew[q] = *(const f32x4*)(ewp + (ekq * 4 + q) * 4);

    float c[8];
#pragma unroll
    for (int q = 0; q < 8; ++q) c[q] = 0.f;

    // stage B slice kt into buffer buf: wave w loads its own 4 fragments
    // (nt = g*8+w), each 1 KB, LDS dst = uniform base + lane*16 (linear).
    auto stage = [&](int kt, int buf) {
#pragma unroll
        for (int q = 0; q < 4; ++q) {
            int nt = q * 8 + w;
            const _Float16* src = Bp + (((size_t)kt * 32 + nt) * 64 + l) * 8;
            __builtin_amdgcn_global_load_lds(
                (const __attribute__((address_space(1))) void*)src,
                (__attribute__((address_space(3))) void*)(smB + buf * 32768 + nt * 1024),
                16, 0, 0);
        }
    };

    stage(0, 0);  // prologue: kt0 -> buf0
    __syncthreads();

    for (int step = 0; step < TSTEPS; ++step) {
        // ---- E: e = relu(x @ Wemb.T + bemb) -> A rows k=0..63 (f16)
        {
            float x0, x1;
            if (step < SEQ) {
                const float* xp = obs + ((size_t)step * PEDS + epg) * 2;
                x0 = xp[0]; x1 = xp[1];
            } else {
                x0 = outs[eped * 2 + 0];
                x1 = outs[eped * 2 + 1];
            }
            half4 vh;
#pragma unroll
            for (int q = 0; q < 4; ++q) {
                float v = fmaf(x0, ew[q][0], fmaf(x1, ew[q][1], ew[q][2]));
                v = v > 0.f ? v : 0.f;
                vh[q] = (_Float16)v;
            }
            int off = (eped * 384 + ekq * 8) ^ ((eped & 7) << 4);
            *(half4*)(smA + off) = vh;
        }
        __syncthreads();  // B1: e (this step) + h (prev step) visible

        // ---- G: gates = A[32x192] @ B[192x512] + bias ; f16 1-pass, 6 kt phases
        f32x4 acc[2][4];  // [mt][gate]
#pragma unroll
        for (int mt = 0; mt < 2; ++mt)
#pragma unroll
            for (int g = 0; g < 4; ++g) {
                acc[mt][g][0] = bias[g]; acc[mt][g][1] = bias[g];
                acc[mt][g][2] = bias[g]; acc[mt][g][3] = bias[g];
            }
#pragma unroll
        for (int kt = 0; kt < 6; ++kt) {
            const int buf  = kt & 1;
            const int ktn  = (kt < 5) ? kt + 1 : 0;  // kt=5 prefetches next step's kt0
            const int bufn = buf ^ 1;
            stage(ktn, bufn);
            // current buf's 4 loads are oldest outstanding; allow the 4 just issued
            asm volatile("s_waitcnt vmcnt(4)" ::: "memory");
            half8 bf[4];
#pragma unroll
            for (int g = 0; g < 4; ++g)
                bf[g] = *((const half8*)(smB + buf * 32768 + (g * 8 + w) * 1024) + l);
#pragma unroll
            for (int mt = 0; mt < 2; ++mt) {
                int ped = mt * 16 + (l & 15);
                int off = (ped * 384 + (kt * 32 + kgrp) * 2) ^ ((ped & 7) << 4);
                half8 ah = *(const half8*)(smA + off);
#pragma unroll
                for (int g = 0; g < 4; ++g)
                    acc[mt][g] = __builtin_amdgcn_mfma_f32_16x16x32_f16(ah, bf[g], acc[mt][g], 0, 0, 0);
            }
        }
        __syncthreads();  // B2: all A reads done before h overwrite

        // ---- S: nonlinearities + c/h update; lane owns (ped = mt*16+lrow+r, j = jlane)
#pragma unroll
        for (int mt = 0; mt < 2; ++mt) {
#pragma unroll
            for (int r = 0; r < 4; ++r) {
                float gi = acc[mt][0][r], gf = acc[mt][1][r];
                float gg = acc[mt][2][r], go = acc[mt][3][r];
                float i_ = sigm(gi), f_ = sigm(gf), g_ = tanhfast(gg), o_ = sigm(go);
                float cn = fmaf(f_, c[mt * 4 + r], i_ * g_);
                c[mt * 4 + r] = cn;
                float hn = o_ * tanhfast(cn);
                int ped = mt * 16 + lrow + r;
                int offb = (ped * 384 + 128 + jlane * 2) ^ ((ped & 7) << 4);
                *(_Float16*)(smA + offb) = (_Float16)hn;
            }
        }

        // ---- O: out = h @ Wout.T + bout (h f16 from LDS)
        if (step >= SEQ - 1) {
            __syncthreads();  // B3: h(step) visible
            if (l < 32) {
                const int oo = w & 1, jq = w >> 1;
                float s = 0.f;
#pragma unroll
                for (int t = 0; t < 4; ++t) {
                    int j = jq * 32 + t * 8;
                    int off = (l * 384 + 128 + j * 2) ^ ((l & 7) << 4);
                    half8 hh8 = *(const half8*)(smA + off);
                    const f32x4 w0 = *(const f32x4*)(Wout + oo * RNN + j);
                    const f32x4 w1 = *(const f32x4*)(Wout + oo * RNN + j + 4);
#pragma unroll
                    for (int i = 0; i < 4; ++i) {
                        s = fmaf((float)hh8[i], w0[i], s);
                        s = fmaf((float)hh8[i + 4], w1[i], s);
                    }
                }
                part[(l * 2 + oo) * 4 + jq] = s;
            }
            __syncthreads();  // B4
            if (tid < 64) {
                int pp = tid & 31, o2 = tid >> 5;
                const float* pr = &part[(pp * 2 + o2) * 4];
                float o = bout[o2] + ((pr[0] + pr[1]) + (pr[2] + pr[3]));
                outs[pp * 2 + o2] = o;
                if (step >= SEQ)
                    out[((size_t)(step - SEQ) * PEDS + (blockIdx.x * PB + pp)) * 2 + o2] = o;
            }
            __syncthreads();  // B5: outs visible for next E
        }
    }
}

extern "C" void kernel_launch(void* const* d_in, const int* in_sizes, int n_in,
                              void* d_out, int out_size, void* d_ws, size_t ws_size,
                              hipStream_t stream) {
    const float* obs  = (const float*)d_in[0];
    const float* Wemb = (const float*)d_in[1];
    const float* bemb = (const float*)d_in[2];
    const float* Wih  = (const float*)d_in[3];
    const float* bih  = (const float*)d_in[4];
    const float* Whh  = (const float*)d_in[5];
    const float* bhh  = (const float*)d_in[6];
    const float* Wout = (const float*)d_in[7];
    const float* bout = (const float*)d_in[8];

    _Float16* Bp  = (_Float16*)d_ws;                 // 98304 f16 = 192 KB
    float*    ewp = (float*)(Bp + 6 * 32 * 64 * 8);  // 64*4 f32 = 1 KB

    prep_kernel<<<(6 * 32 * 64 * 8 + 255) / 256, 256, 0, stream>>>(Wih, Whh, Wemb, bemb, Bp, ewp);
    lstm_kernel<<<PEDS / PB, NT, 0, stream>>>(obs, ewp, bih, bhh, Bp, Wout, bout, (float*)d_out);
}